// Round 7
// baseline (316.260 us; speedup 1.0000x reference)
//
#include <hip/hip_runtime.h>
#include <hip/hip_bf16.h>

typedef unsigned short u16;
typedef unsigned int u32;
typedef float floatx4 __attribute__((ext_vector_type(4)));
typedef __bf16 bf16x8 __attribute__((ext_vector_type(8)));
typedef u16 ushort4v __attribute__((ext_vector_type(4)));
typedef u16 ushort8v __attribute__((ext_vector_type(8)));
typedef u32 u32x2 __attribute__((ext_vector_type(2)));

#define DEVI static __device__ __forceinline__

DEVI u16 f2bf(float f) {
    u32 u = __builtin_bit_cast(u32, f);
    u += 0x7fffu + ((u >> 16) & 1u);   // round-to-nearest-even
    return (u16)(u >> 16);
}
DEVI float bf2f(u16 h) { return __builtin_bit_cast(float, (u32)h << 16); }

DEVI float fexp2(float x) { return __builtin_amdgcn_exp2f(x); }  // v_exp_f32

// packed f32->bf16 convert (RTNE), one VALU op for two values
DEVI u32 cvtpk_bf16(float lo, float hi) {
    u32 r;
    asm("v_cvt_pk_bf16_f32 %0, %1, %2" : "=v"(r) : "v"(lo), "v"(hi));
    return r;
}

// async global->LDS, 16B per lane. dst must be wave-uniform base; HW adds lane*16.
DEVI void async_cp16(const u16* g, u16* l) {
    __builtin_amdgcn_global_load_lds((const __attribute__((address_space(1))) u32*)g,
                                     (__attribute__((address_space(3))) u32*)l, 16, 0, 0);
}

template<int N> DEVI void wait_vmcnt() {
    if constexpr (N == 0)      asm volatile("s_waitcnt vmcnt(0)" ::: "memory");
    else if constexpr (N == 2) asm volatile("s_waitcnt vmcnt(2)" ::: "memory");
    else if constexpr (N == 3) asm volatile("s_waitcnt vmcnt(3)" ::: "memory");
    else if constexpr (N == 4) asm volatile("s_waitcnt vmcnt(4)" ::: "memory");
    else if constexpr (N == 6) asm volatile("s_waitcnt vmcnt(6)" ::: "memory");
    else static_assert(N == 0, "add vmcnt case");
}

#define PH_BAR() asm volatile("s_barrier" ::: "memory")

// square-band XCD swizzle: 8 XCD cells = 4(m) x 2(x). Needs gy%4==0, gx%2==0.
// Shrinks per-XCD operand working set vs full-width m-bands (L2 is 4MB/XCD).
DEVI void xcd_swizzle(int& bx, int& by, int gx, int gy) {
    int L = by * gx + bx;
    int xcd = L & 7, s = L >> 3;
    int gh = gy >> 2, xh = gx >> 1;
    int mg = xcd & 3, ng = xcd >> 2;
    by = mg * gh + s % gh;
    bx = ng * xh + s / gh;
}

// ---------------------------------------------------------------------------
// GEMM 128-tile: counted-vmcnt 2-deep, 3 LDS buffers (flat smem).
// Coalesced bf16 epilogue via swizzled LDS transpose image (R5 winner).
// ---------------------------------------------------------------------------
template<int BM, int BN, int RW, int CW, bool QKV3, int NSPLIT, bool XSWZ,
         bool BIAS, bool RELU, bool RESID, bool OBF16, bool VTW>
__global__ __launch_bounds__(256) void gemm_nt(
    const u16* __restrict__ A,
    const u16* __restrict__ W0, const u16* __restrict__ W1, const u16* __restrict__ W2,
    const float* __restrict__ bias, const float* __restrict__ resid,
    void* __restrict__ o0, void* __restrict__ o1, void* __restrict__ o2,
    void* __restrict__ o3, int K, int lda, int Nper, int NX)
{
    static_assert(RW * CW == 4, "4 waves");
    constexpr int WM = BM / RW, WN = BN / CW;
    constexpr int MI = WM / 16, NI = WN / 16;
    constexpr int LPT = BM / 64 + BN / 64;
    constexpr int ASZ = 3 * BM * 32;          // u16 units
    constexpr int BSZ = 3 * BN * 32;
    __shared__ __align__(16) u16 smem[ASZ + BSZ];
    u16* Asm = smem;
    u16* Bsm = smem + ASZ;
    const int tid = threadIdx.x;
    const int w = tid >> 6, lane = tid & 63;
    const int q = lane >> 4, ml = lane & 15;
    const int wr = w / CW, wc = w % CW;
    int bx = blockIdx.x, by = blockIdx.y;
    if (XSWZ) xcd_swizzle(bx, by, gridDim.x, gridDim.y);
    const int m0 = by * BM;
    size_t kbase = 0;
    const u16* W = W0;
    void* outp = o0;
    if (NSPLIT > 1) {
        int part = bx / NX; bx -= part * NX; kbase = (size_t)part * K;
        outp = (part == 0) ? o0 : (part == 1 ? o1 : (part == 2 ? o2 : o3));
    }
    int n0 = bx * BN;
    bool vwrite = false;
    if (QKV3) {
        int sel = n0 / Nper;
        n0 -= sel * Nper;
        W = (sel == 0) ? W0 : (sel == 1 ? W1 : W2);
        outp = (sel == 0) ? o0 : (sel == 1 ? o1 : o2);
        if (VTW) vwrite = (sel == 2);
    }

    auto stage = [&](int buf, int kt) {
#pragma unroll
        for (int p = 0; p < BM / 64; ++p) {
            int g = p * 256 + tid;
            int r = g >> 2, s = g & 3;
            int c = s ^ ((r >> 1) & 3);
            async_cp16(A + (size_t)(m0 + r) * lda + kbase + kt + c * 8,
                       &Asm[buf * (BM * 32) + (p * 256 + w * 64) * 8]);
        }
#pragma unroll
        for (int p = 0; p < BN / 64; ++p) {
            int g = p * 256 + tid;
            int r = g >> 2, s = g & 3;
            int c = s ^ ((r >> 1) & 3);
            async_cp16(W + (size_t)(n0 + r) * lda + kbase + kt + c * 8,
                       &Bsm[buf * (BN * 32) + (p * 256 + w * 64) * 8]);
        }
    };

    const floatx4 fzero = {0.f, 0.f, 0.f, 0.f};
    floatx4 acc[MI][NI];
#pragma unroll
    for (int i = 0; i < MI; ++i)
#pragma unroll
        for (int j = 0; j < NI; ++j) acc[i][j] = fzero;

    const int nt = K >> 5;
    stage(0, 0);
    stage(1, 32);
    int cb = 0, nb = 2;
    for (int it = 0, kt = 0; it < nt; ++it, kt += 32) {
        wait_vmcnt<LPT>();
        __builtin_amdgcn_s_barrier();
        __builtin_amdgcn_sched_barrier(0);
        int ktn = kt + 64; if (ktn > K - 32) ktn = K - 32;   // clamped dup
        stage(nb, ktn);
        __builtin_amdgcn_sched_barrier(0);
        const u16* Asb = &Asm[cb * (BM * 32)];
        const u16* Bsb = &Bsm[cb * (BN * 32)];
        bf16x8 af[MI], bfr[NI];
#pragma unroll
        for (int i = 0; i < MI; ++i) {
            int rm = wr * WM + i * 16 + ml;
            int s = q ^ ((rm >> 1) & 3);
            af[i] = *(const bf16x8*)&Asb[(rm * 4 + s) * 8];
        }
#pragma unroll
        for (int j = 0; j < NI; ++j) {
            int rn = wc * WN + j * 16 + ml;
            int s = q ^ ((rn >> 1) & 3);
            bfr[j] = *(const bf16x8*)&Bsb[(rn * 4 + s) * 8];
        }
#pragma unroll
        for (int i = 0; i < MI; ++i)
#pragma unroll
            for (int j = 0; j < NI; ++j)
                acc[i][j] = __builtin_amdgcn_mfma_f32_16x16x32_bf16(af[i], bfr[j], acc[i][j], 0, 0, 0);
        cb = cb == 2 ? 0 : cb + 1;
        nb = nb == 2 ? 0 : nb + 1;
    }

    wait_vmcnt<0>();   // drain clamped dup stages (also frees LDS for reuse)

    if constexpr (OBF16) {
        __builtin_amdgcn_s_barrier();   // all waves' DMA drained -> LDS free
        char* T = (char*)smem;
        if (VTW && vwrite) {
            // LDS image [BN n][BM m] bf16; packed 8B writes (4 consecutive m)
#pragma unroll
            for (int j = 0; j < NI; ++j) {
                int nl = wc * WN + j * 16 + ml;
#pragma unroll
                for (int i = 0; i < MI; ++i) {
                    int m4 = wr * WM + i * 16 + q * 4;
                    u32x2 pk = {(u32)f2bf(acc[i][j][0]) | ((u32)f2bf(acc[i][j][1]) << 16),
                                (u32)f2bf(acc[i][j][2]) | ((u32)f2bf(acc[i][j][3]) << 16)};
                    *(u32x2*)(T + nl * (BM * 2) + ((m4 * 2) ^ ((nl & 15) << 4))) = pk;
                }
            }
            __syncthreads();
            const int bb = m0 >> 11, sres = m0 & 2047;
            constexpr int CPR = BM / 8, RPP = 256 / CPR;
#pragma unroll
            for (int p = 0; p < BN / RPP; ++p) {
                int nr = p * RPP + (tid / CPR);
                int c0 = (tid % CPR) * 8;
                bf16x8 vv = *(const bf16x8*)(T + nr * (BM * 2) + ((c0 * 2) ^ ((nr & 15) << 4)));
                *(bf16x8*)&((u16*)o3)[(size_t)(bb * 1024 + n0 + nr) * 2048 + sres + c0] = vv;
            }
        } else {
            // LDS image [BM row][BN col] bf16
#pragma unroll
            for (int j = 0; j < NI; ++j) {
                int col = wc * WN + j * 16 + ml;
                float bj = 0.f;
                if (BIAS) bj = bias[n0 + col];
#pragma unroll
                for (int i = 0; i < MI; ++i) {
#pragma unroll
                    for (int r = 0; r < 4; ++r) {
                        int row = wr * WM + i * 16 + q * 4 + r;
                        float v = acc[i][j][r] + bj;
                        if (RELU) v = fmaxf(v, 0.f);
                        *(u16*)(T + row * (BN * 2) + ((col * 2) ^ ((row & 15) << 4))) = f2bf(v);
                    }
                }
            }
            __syncthreads();
            constexpr int CPR = BN / 8, RPP = 256 / CPR;
#pragma unroll
            for (int p = 0; p < BM / RPP; ++p) {
                int rr = p * RPP + (tid / CPR);
                int c0 = (tid % CPR) * 8;
                bf16x8 vv = *(const bf16x8*)(T + rr * (BN * 2) + ((c0 * 2) ^ ((rr & 15) << 4)));
                *(bf16x8*)&((u16*)outp)[(size_t)(m0 + rr) * Nper + n0 + c0] = vv;
            }
        }
    } else {
        // fp32 out (+resid): 16 lanes x 4B = 64B runs, already line-coalesced
#pragma unroll
        for (int j = 0; j < NI; ++j) {
            int gn = n0 + wc * WN + j * 16 + ml;
            float bj = 0.f;
            if (BIAS) bj = bias[gn];
#pragma unroll
            for (int i = 0; i < MI; ++i) {
                int gm0 = m0 + wr * WM + i * 16 + q * 4;
#pragma unroll
                for (int r = 0; r < 4; ++r) {
                    size_t idx = (size_t)(gm0 + r) * Nper + gn;
                    float v = acc[i][j][r] + bj;
                    if (RELU) v = fmaxf(v, 0.f);
                    if (RESID) v += resid[idx];
                    ((float*)outp)[idx] = v;
                }
            }
        }
    }
}

// ---------------------------------------------------------------------------
// gemm8p: 256x256 tile, BK=64, 8 waves, 8-phase counted-vmcnt schedule.
// Flat 128KB smem; coalesced epilogue via swizzled LDS transpose (R5 winner).
// ---------------------------------------------------------------------------
template<bool QKV3, int NSPLIT, bool BIAS, bool RELU, bool VTW>
__global__ __launch_bounds__(512, 2) void gemm8p(
    const u16* __restrict__ A,
    const u16* __restrict__ W0, const u16* __restrict__ W1, const u16* __restrict__ W2,
    const float* __restrict__ bias,
    void* __restrict__ o0, void* __restrict__ o1, void* __restrict__ o2,
    void* __restrict__ o3, int K, int lda, int Nper, int NX)
{
    __shared__ __align__(16) u16 smem[65536];   // As: [0,32768) Bs: [32768,65536)
    u16* Asm = smem;
    u16* Bsm = smem + 32768;
    const int tid = threadIdx.x;
    const int w = tid >> 6, lane = tid & 63;
    const int q = lane >> 4, ml = lane & 15;
    const int wr = w >> 2, wc = w & 3;             // 2 M-waves x 4 N-waves
    int bx = blockIdx.x, by = blockIdx.y;
    xcd_swizzle(bx, by, gridDim.x, gridDim.y);
    const int m0 = by * 256;
    size_t kbase = 0;
    const u16* W = W0;
    void* outp = o0;
    if (NSPLIT > 1) {
        int part = bx / NX; bx -= part * NX; kbase = (size_t)part * K;
        outp = (part == 0) ? o0 : (part == 1 ? o1 : (part == 2 ? o2 : o3));
    }
    int n0 = bx * 256;
    if (QKV3) {
        int sel = n0 / Nper; n0 -= sel * Nper;
        W = (sel == 0) ? W0 : (sel == 1 ? W1 : W2);
        outp = (sel == 0) ? o0 : (sel == 1 ? o1 : o2);
    }

    auto stA = [&](int d, int kh, int kt) {
#pragma unroll
        for (int p = 0; p < 2; ++p) {
            int c = p * 512 + tid;
            int r = c >> 2;
            int sc = (c & 3) ^ ((r >> 1) & 3);
            async_cp16(A + (size_t)(m0 + r) * lda + kbase + kt + kh * 32 + sc * 8,
                       &Asm[(d * 2 + kh) * 8192 + (p * 512 + w * 64) * 8]);
        }
    };
    auto stB = [&](int d, int kh, int kt) {
#pragma unroll
        for (int p = 0; p < 2; ++p) {
            int c = p * 512 + tid;
            int r = c >> 2;
            int sc = (c & 3) ^ ((r >> 1) & 3);
            async_cp16(W + (size_t)(n0 + r) * lda + kbase + kt + kh * 32 + sc * 8,
                       &Bsm[(d * 2 + kh) * 8192 + (p * 512 + w * 64) * 8]);
        }
    };
    auto rdA = [&](int d, int kh, int i) -> bf16x8 {
        int rm = wr * 128 + i * 16 + ml;
        return *(const bf16x8*)&Asm[(d * 2 + kh) * 8192 + (rm * 4 + (q ^ ((rm >> 1) & 3))) * 8];
    };
    auto rdB = [&](int d, int kh, int j) -> bf16x8 {
        int rn = wc * 64 + j * 16 + ml;
        return *(const bf16x8*)&Bsm[(d * 2 + kh) * 8192 + (rn * 4 + (q ^ ((rn >> 1) & 3))) * 8];
    };

    const floatx4 fzero = {0.f, 0.f, 0.f, 0.f};
    floatx4 acc[8][4];
#pragma unroll
    for (int i = 0; i < 8; ++i)
#pragma unroll
        for (int j = 0; j < 4; ++j) acc[i][j] = fzero;

#define PHASE(d, kh, ih, STG, VM)                                              \
    {                                                                          \
        if (ih == 0) {                                                         \
            _Pragma("unroll")                                                  \
            for (int j = 0; j < 4; ++j) bfr[j] = rdB(d, kh, j);                \
        }                                                                      \
        _Pragma("unroll")                                                      \
        for (int ii = 0; ii < 4; ++ii) af[ii] = rdA(d, kh, (ih) * 4 + ii);     \
        STG;                                                                   \
        if (VM) wait_vmcnt<4>();                                               \
        PH_BAR();                                                              \
        __builtin_amdgcn_s_setprio(1);                                         \
        _Pragma("unroll")                                                      \
        for (int ii = 0; ii < 4; ++ii)                                         \
            _Pragma("unroll")                                                  \
            for (int j = 0; j < 4; ++j)                                        \
                acc[(ih) * 4 + ii][j] = __builtin_amdgcn_mfma_f32_16x16x32_bf16( \
                    af[ii], bfr[j], acc[(ih) * 4 + ii][j], 0, 0, 0);           \
        __builtin_amdgcn_s_setprio(0);                                         \
        PH_BAR();                                                              \
    }

    const int R = K >> 7;
    stA(0, 0, 0); stB(0, 0, 0); stA(0, 1, 0); stB(0, 1, 0);
    wait_vmcnt<0>();
    PH_BAR();

    for (int rr = 0; rr < R; ++rr) {
        const int kt1 = rr * 128 + 64;
        const int kt2 = (rr * 128 + 128 <= K - 64) ? rr * 128 + 128 : K - 64;
        bf16x8 af[4], bfr[4];
        PHASE(0, 0, 0, stA(1, 0, kt1), 0)
        PHASE(0, 0, 1, stB(1, 0, kt1), 1)
        PHASE(0, 1, 0, stA(1, 1, kt1), 0)
        PHASE(0, 1, 1, stB(1, 1, kt1), 1)
        PHASE(1, 0, 0, stA(0, 0, kt2), 0)
        PHASE(1, 0, 1, stB(0, 0, kt2), 1)
        PHASE(1, 1, 0, stA(0, 1, kt2), 0)
        PHASE(1, 1, 1, stB(0, 1, kt2), 1)
    }
#undef PHASE
    wait_vmcnt<0>();                 // drain clamped dup stages
    __builtin_amdgcn_s_barrier();    // LDS now free for the transpose image

    // epilogue via LDS transpose: [256 rows][512 B] swizzled image
    char* T = (char*)smem;
#pragma unroll
    for (int j = 0; j < 4; ++j) {
        int col = wc * 64 + j * 16 + ml;
        float bj = 0.f;
        if (BIAS) bj = bias[n0 + col];
#pragma unroll
        for (int i = 0; i < 8; ++i) {
#pragma unroll
            for (int r = 0; r < 4; ++r) {
                int row = wr * 128 + i * 16 + q * 4 + r;
                float v = acc[i][j][r] + bj;
                if (RELU) v = fmaxf(v, 0.f);
                *(u16*)(T + row * 512 + ((col * 2) ^ ((row & 15) << 5))) = f2bf(v);
            }
        }
    }
    __syncthreads();
#pragma unroll
    for (int p = 0; p < 16; ++p) {
        int rr = p * 16 + (tid >> 5);
        int c0 = (tid & 31) * 8;
        bf16x8 vv = *(const bf16x8*)(T + rr * 512 + ((c0 * 2) ^ ((rr & 15) << 5)));
        *(bf16x8*)&((u16*)outp)[(size_t)(m0 + rr) * Nper + n0 + c0] = vv;
    }
}

// ---------------------------------------------------------------------------
// Flash attention v11 = v10 + lsum via ones-row MFMA.
// The PV B-operand (pfrag) already holds P; mfma(ones, pfrag, lacc) computes
// sum_k P[k][query] in every output row -> replaces 28 VALU adds/iter and the
// final cross-lane shuffles (each lane's lacc[qg][0] is the complete tile sum
// for its query). Denominator now sums bf16-rounded P (matches PV numerator).
// XCD-grouping block swizzle (K/V L2-resident; FETCH 12 MB) unchanged.
// Q,K: [b*2048+s][h*64+d].  Vt: [b*1024+h*64+d][s].
// ---------------------------------------------------------------------------
__global__ __launch_bounds__(256, 2) void flash9(
    const u16* __restrict__ Q, const u16* __restrict__ Kg,
    const u16* __restrict__ Vt, const float* __restrict__ biasv,
    u16* __restrict__ O)
{
    __shared__ __align__(16) u16 smem[24576];
    const int tid = threadIdx.x;
    const int w = tid >> 6, lane = tid & 63;
    const int qw = w & 1, kv = w >> 1;
    const int q = lane >> 4, ml = lane & 15;
    int bx = blockIdx.x, by = blockIdx.y;
    {   // XCD-grouping: L%8 = XCD; give each XCD 4 contiguous bh values
        int L = by * 16 + bx;            // gridDim.x == 16
        int xcd = L & 7, s = L >> 3;     // s in 0..63
        by = xcd * 4 + (s >> 4);         // bh
        bx = s & 15;                     // q-block
    }
    const int b = by >> 4, h = by & 15;
    const size_t rowQ = (size_t)(b * 2048 + bx * 128);
    const float KSC = 0.125f * 1.4426950408889634f;
    const floatx4 fzero = {0.f, 0.f, 0.f, 0.f};
    const ushort8v onesv = {0x3F80, 0x3F80, 0x3F80, 0x3F80,
                            0x3F80, 0x3F80, 0x3F80, 0x3F80};
    const bf16x8 vone = __builtin_bit_cast(bf16x8, onesv);

    bf16x8 qa[4][2];
#pragma unroll
    for (int qg = 0; qg < 4; ++qg)
#pragma unroll
        for (int c = 0; c < 2; ++c)
            qa[qg][c] = *(const bf16x8*)&Q[(rowQ + qw * 64 + qg * 16 + ml) * 1024
                                           + h * 64 + q * 8 + c * 32];

    auto stage = [&](int buf, int it) {
        {
            int row = tid >> 3, sl = tid & 7;
            int ch = sl ^ ((row & 3) | (((row >> 3) & 1) << 2));
#pragma unroll
            for (int hf = 0; hf < 2; ++hf)
                async_cp16(Kg + (size_t)(b * 2048 + hf * 1024 + it * 32 + row) * 1024
                               + h * 64 + ch * 8,
                           &smem[(hf * 3 + buf) * 2048 + w * 512]);
        }
        {
            int row = tid >> 2, sl = tid & 3;
            int ch = sl ^ ((row >> 1) & 3);
#pragma unroll
            for (int hf = 0; hf < 2; ++hf)
                async_cp16(Vt + (size_t)(b * 1024 + h * 64 + row) * 2048
                               + hf * 1024 + it * 32 + ch * 8,
                           &smem[12288 + (hf * 3 + buf) * 2048 + w * 512]);
        }
    };

    floatx4 oacc[4][4];
    floatx4 lacc[4];
#pragma unroll
    for (int qg = 0; qg < 4; ++qg) {
        lacc[qg] = fzero;
#pragma unroll
        for (int d = 0; d < 4; ++d) oacc[qg][d] = fzero;
    }

    const int swk = (ml & 3) | (((ml >> 2) & 1) << 2);
    const int re = ((ml >> 2) << 3) + (ml & 3);

    stage(0, 0);
    stage(1, 1);
    int cb = 0, nb = 2;
    for (int it = 0; it < 32; ++it) {
        asm volatile("s_waitcnt vmcnt(4)" ::: "memory");
        __builtin_amdgcn_s_barrier();
        __builtin_amdgcn_sched_barrier(0);
        const int s0 = kv * 1024 + it * 32;
        const float4 be = *(const float4*)&biasv[b * 2048 + s0 + q * 8];
        const float4 bo = *(const float4*)&biasv[b * 2048 + s0 + q * 8 + 4];
        __builtin_amdgcn_sched_barrier(0);
        stage(nb, it + 2 < 32 ? it + 2 : 31);

        const u16* Kb = &smem[(kv * 3 + cb) * 2048];
        const u16* Vb = &smem[12288 + (kv * 3 + cb) * 2048];

        bf16x8 ke0 = *(const bf16x8*)&Kb[(re + 0) * 64 + ((0 + q) ^ swk) * 8];
        bf16x8 ke1 = *(const bf16x8*)&Kb[(re + 0) * 64 + ((4 + q) ^ swk) * 8];
        bf16x8 ko0 = *(const bf16x8*)&Kb[(re + 4) * 64 + ((0 + q) ^ swk) * 8];
        bf16x8 ko1 = *(const bf16x8*)&Kb[(re + 4) * 64 + ((4 + q) ^ swk) * 8];
        bf16x8 pfrag[4];
#pragma unroll
        for (int qg = 0; qg < 4; ++qg) {
            floatx4 te = fzero, to = fzero;
            te = __builtin_amdgcn_mfma_f32_16x16x32_bf16(ke0, qa[qg][0], te, 0, 0, 0);
            te = __builtin_amdgcn_mfma_f32_16x16x32_bf16(ke1, qa[qg][1], te, 0, 0, 0);
            to = __builtin_amdgcn_mfma_f32_16x16x32_bf16(ko0, qa[qg][0], to, 0, 0, 0);
            to = __builtin_amdgcn_mfma_f32_16x16x32_bf16(ko1, qa[qg][1], to, 0, 0, 0);
            float pe0 = fexp2(fmaf(te[0], KSC, be.x));
            float pe1 = fexp2(fmaf(te[1], KSC, be.y));
            float pe2 = fexp2(fmaf(te[2], KSC, be.z));
            float pe3 = fexp2(fmaf(te[3], KSC, be.w));
            float po0 = fexp2(fmaf(to[0], KSC, bo.x));
            float po1 = fexp2(fmaf(to[1], KSC, bo.y));
            float po2 = fexp2(fmaf(to[2], KSC, bo.z));
            float po3 = fexp2(fmaf(to[3], KSC, bo.w));
            u32 pk[4];
            pk[0] = cvtpk_bf16(pe0, pe1);
            pk[1] = cvtpk_bf16(pe2, pe3);
            pk[2] = cvtpk_bf16(po0, po1);
            pk[3] = cvtpk_bf16(po2, po3);
            pfrag[qg] = __builtin_bit_cast(bf16x8, *(uint4*)pk);
            lacc[qg] = __builtin_amdgcn_mfma_f32_16x16x32_bf16(
                vone, pfrag[qg], lacc[qg], 0, 0, 0);
        }
#pragma unroll
        for (int dt = 0; dt < 4; ++dt) {
            int vrow = dt * 16 + ml;
            bf16x8 vf = *(const bf16x8*)&Vb[vrow * 32 + ((q ^ ((vrow >> 1) & 3)) * 8)];
#pragma unroll
            for (int qg = 0; qg < 4; ++qg)
                oacc[qg][dt] = __builtin_amdgcn_mfma_f32_16x16x32_bf16(
                    vf, pfrag[qg], oacc[qg][dt], 0, 0, 0);
        }
        cb = cb == 2 ? 0 : cb + 1;
        nb = nb == 2 ? 0 : nb + 1;
    }

    __syncthreads();
    float* sO = (float*)smem;
    float* sL = (float*)smem + 8192;
    if (kv == 1) {
#pragma unroll
        for (int qg = 0; qg < 4; ++qg) {
            sL[(qw * 4 + qg) * 64 + lane] = lacc[qg][0];
#pragma unroll
            for (int dt = 0; dt < 4; ++dt)
                *(floatx4*)&sO[((qw * 4 + qg) * 4 + dt) * 256 + lane * 4] = oacc[qg][dt];
        }
    }
    __syncthreads();
    if (kv == 1) return;
#pragma unroll
    for (int qg = 0; qg < 4; ++qg) {
        float ls = lacc[qg][0] + sL[(qw * 4 + qg) * 64 + lane];
#pragma unroll
        for (int dt = 0; dt < 4; ++dt)
            oacc[qg][dt] += *(const floatx4*)&sO[((qw * 4 + qg) * 4 + dt) * 256 + lane * 4];
        const float rcp = 1.f / ls;
        const size_t row = rowQ + qw * 64 + qg * 16 + ml;
#pragma unroll
        for (int dt = 0; dt < 4; ++dt)
#pragma unroll
            for (int rp = 0; rp < 4; rp += 2) {
                u32 pk = (u32)f2bf(oacc[qg][dt][rp] * rcp)
                       | ((u32)f2bf(oacc[qg][dt][rp + 1] * rcp) << 16);
                *(u32*)&O[row * 1024 + h * 64 + dt * 16 + q * 4 + rp] = pk;
            }
    }
}

// LayerNorm (torch semantics: ddof=1 variance, eps added to std), fp32 -> bf16
DEVI void ln_row(const float* __restrict__ x, float ga, float gb,
                 u16* __restrict__ y, int row, int tid)
{
    const float4 v = ((const float4*)(x + (size_t)row * 1024))[tid];
    float s = v.x + v.y + v.z + v.w;
    float ss = v.x * v.x + v.y * v.y + v.z * v.z + v.w * v.w;
#pragma unroll
    for (int d = 1; d < 64; d <<= 1) { s += __shfl_xor(s, d, 64); ss += __shfl_xor(ss, d, 64); }
    __shared__ float ps[4], pss[4];
    const int w = tid >> 6, lane = tid & 63;
    if (lane == 0) { ps[w] = s; pss[w] = ss; }
    __syncthreads();
    s = ps[0] + ps[1] + ps[2] + ps[3];
    ss = pss[0] + pss[1] + pss[2] + pss[3];
    float mean = s * (1.f / 1024.f);
    float var = fmaxf((ss - s * mean) * (1.f / 1023.f), 0.f);
    float sc = ga / (sqrtf(var) + 1e-6f);
    ushort4v o;
    o[0] = f2bf((v.x - mean) * sc + gb);
    o[1] = f2bf((v.y - mean) * sc + gb);
    o[2] = f2bf((v.z - mean) * sc + gb);
    o[3] = f2bf((v.w - mean) * sc + gb);
    ((ushort4v*)(y + (size_t)row * 1024))[tid] = o;
}

__global__ __launch_bounds__(256) void ln_bf16(const float* __restrict__ x,
    const float* __restrict__ ga, const float* __restrict__ gb, u16* __restrict__ y)
{
    ln_row(x, ga[0], gb[0], y, blockIdx.x, threadIdx.x);
}

// prep: weight casts (blocks 0..12287) + mask bias (12288..12303) + LN1 (12304..16399)
__global__ __launch_bounds__(256) void prep(
    const float* __restrict__ wq, const float* __restrict__ wk,
    const float* __restrict__ wv, const float* __restrict__ wo,
    const float* __restrict__ w1, const float* __restrict__ w2,
    u16* __restrict__ wqb, u16* __restrict__ wkb, u16* __restrict__ wvb,
    u16* __restrict__ wob, u16* __restrict__ w1b, u16* __restrict__ w2b,
    const int* __restrict__ m, float* __restrict__ biasv,
    const float* __restrict__ src, const float* __restrict__ a1,
    const float* __restrict__ be1, u16* __restrict__ xln1)
{
    const int bx = blockIdx.x;
    if (bx < 12288) {
        size_t i = (size_t)bx * 256 + threadIdx.x;   // float4 index
        const float* s; u16* d; size_t off;
        if (i < 262144)       { s = wq; d = wqb; off = i; }
        else if (i < 524288)  { s = wk; d = wkb; off = i - 262144; }
        else if (i < 786432)  { s = wv; d = wvb; off = i - 524288; }
        else if (i < 1048576) { s = wo; d = wob; off = i - 786432; }
        else if (i < 2097152) { s = w1; d = w1b; off = i - 1048576; }
        else                  { s = w2; d = w2b; off = i - 2097152; }
        float4 v = ((const float4*)s)[off];
        ushort4v o = {f2bf(v.x), f2bf(v.y), f2bf(v.z), f2bf(v.w)};
        ((ushort4v*)d)[off] = o;
    } else if (bx < 12304) {
        int i = (bx - 12288) * 256 + threadIdx.x;
        biasv[i] = m[i] ? 0.f : -1.442695e9f;
    } else {
        ln_row(src, a1[0], be1[0], xln1, bx - 12304, threadIdx.x);
    }
}

// FF2 finish: out = (bf16 partials P0+P1+P2+P3) + b2[col] + resid
__global__ __launch_bounds__(256) void ff2_fin(
    const u16* __restrict__ p0, const u16* __restrict__ p1,
    const u16* __restrict__ p2, const u16* __restrict__ p3,
    const float* __restrict__ b2, const float* __restrict__ resid,
    float* __restrict__ out)
{
    const size_t i = (size_t)blockIdx.x * 256 + threadIdx.x;   // float4 index
    ushort4v a = *(const ushort4v*)&p0[i * 4];
    ushort4v b = *(const ushort4v*)&p1[i * 4];
    ushort4v c = *(const ushort4v*)&p2[i * 4];
    ushort4v d = *(const ushort4v*)&p3[i * 4];
    float4 r = ((const float4*)resid)[i];
    float4 bb = ((const float4*)b2)[i & 255];
    float4 o;
    o.x = ((bf2f(a[0]) + bf2f(b[0])) + (bf2f(c[0]) + bf2f(d[0]))) + r.x + bb.x;
    o.y = ((bf2f(a[1]) + bf2f(b[1])) + (bf2f(c[1]) + bf2f(d[1]))) + r.y + bb.y;
    o.z = ((bf2f(a[2]) + bf2f(b[2])) + (bf2f(c[2]) + bf2f(d[2]))) + r.z + bb.z;
    o.w = ((bf2f(a[3]) + bf2f(b[3])) + (bf2f(c[3]) + bf2f(d[3]))) + r.w + bb.w;
    ((float4*)out)[i] = o;
}

extern "C" void kernel_launch(void* const* d_in, const int* in_sizes, int n_in,
                              void* d_out, int out_size, void* d_ws, size_t ws_size,
                              hipStream_t stream)
{
    const float* src = (const float*)d_in[0];
    const int* msk   = (const int*)d_in[1];
    const float* wq  = (const float*)d_in[2];
    const float* wk  = (const float*)d_in[3];
    const float* wv  = (const float*)d_in[4];
    const float* wo  = (const float*)d_in[5];
    const float* w1  = (const float*)d_in[6];
    const float* b1  = (const float*)d_in[7];
    const float* w2  = (const float*)d_in[8];
    const float* b2  = (const float*)d_in[9];
    const float* a1  = (const float*)d_in[10];
    const float* be1 = (const float*)d_in[11];
    const float* a2  = (const float*)d_in[12];
    const float* be2 = (const float*)d_in[13];
    float* out = (float*)d_out;

    char* ws = (char*)d_ws;
    const size_t MB = (size_t)1 << 20;
    u16* wqb  = (u16*)(ws + 0 * MB);
    u16* wkb  = (u16*)(ws + 2 * MB);
    u16* wvb  = (u16*)(ws + 4 * MB);
    u16* wob  = (u16*)(ws + 6 * MB);
    u16* w1b  = (u16*)(ws + 8 * MB);    // 8..16
    u16* w2b  = (u16*)(ws + 16 * MB);   // 16..24 (live through FF2)
    u16* xln1 = (u16*)(ws + 24 * MB);   // 24..32; dead after QKV; aliased by attn
    u16* attn = xln1;
    u16* Qb   = (u16*)(ws + 32 * MB);   // 32..40; dead after flash; aliased by xln2
    u16* xln2 = Qb;
    u16* Kb   = (u16*)(ws + 40 * MB);   // 40..48
    u16* Vt   = (u16*)(ws + 56 * MB);   // 56..64 (written directly by QKV VTW)
    float* biasv = (float*)(ws + 64 * MB);  // 16 KB in 64..72 spare
    u16* h1   = (u16*)(ws + 40 * MB);   // 32 MB: 40..72 (Kb/Vt dead by then)
    float* src2 = (float*)(ws + 72 * MB); // 16 MB: 72..88
    // FF2 bf16 partials (8 MB each) in regions dead by FF2 time:
    u16* P0 = (u16*)(ws + 0 * MB);    // wq..wo casts (dead after O-proj)
    u16* P1 = (u16*)(ws + 8 * MB);    // w1b (dead after FF1)
    u16* P2 = (u16*)(ws + 24 * MB);   // attn (dead after O-proj)
    u16* P3 = (u16*)(ws + 32 * MB);   // xln2 (dead after FF1)

    // fused: weight casts + mask bias + LN1
    prep<<<16400, 256, 0, stream>>>(wq, wk, wv, wo, w1, w2,
                                    wqb, wkb, wvb, wob, w1b, w2b,
                                    msk, biasv, src, a1, be1, xln1);

    // fused QKV (128-tile, 768 blocks, fills chip): V written transposed to Vt
    gemm_nt<128, 128, 2, 2, true, 1, true, false, false, false, true, true><<<dim3(24, 32), 256, 0, stream>>>(
        xln1, wqb, wkb, wvb, nullptr, nullptr, Qb, Kb, nullptr, Vt, 1024, 1024, 1024, 0);

    flash9<<<dim3(16, 32), 256, 0, stream>>>(Qb, Kb, Vt, biasv, attn);

    // O-projection + residual (fp32) — 128x64 tile path
    gemm_nt<128, 64, 4, 1, false, 1, true, false, false, true, false, false><<<dim3(16, 32), 256, 0, stream>>>(
        attn, wob, nullptr, nullptr, nullptr, src, src2, nullptr, nullptr, nullptr,
        1024, 1024, 1024, 0);

    ln_bf16<<<4096, 256, 0, stream>>>(src2, a2, be2, xln2);

    // FF1 (8-phase, 256 blocks = 1/CU): bias + ReLU -> bf16
    gemm8p<false, 1, true, true, false><<<dim3(16, 16), 512, 0, stream>>>(
        xln2, w1b, nullptr, nullptr, b1, h1, nullptr, nullptr, nullptr,
        1024, 1024, 4096, 0);

    // FF2 (8-phase, split-K=4, 256 blocks = 1/CU) into bf16 partials
    gemm8p<false, 4, false, false, false><<<dim3(16, 16), 512, 0, stream>>>(
        h1, w2b, nullptr, nullptr, nullptr, P0, P1, P2, P3,
        1024, 4096, 1024, 4);

    // out = P0+P1+P2+P3 + b2 + src2
    ff2_fin<<<4096, 256, 0, stream>>>(P0, P1, P2, P3, b2, src2, out);
}

// Round 8
// 304.656 us; speedup vs baseline: 1.0381x; 1.0381x over previous
//
#include <hip/hip_runtime.h>
#include <hip/hip_bf16.h>

typedef unsigned short u16;
typedef unsigned int u32;
typedef float floatx4 __attribute__((ext_vector_type(4)));
typedef __bf16 bf16x8 __attribute__((ext_vector_type(8)));
typedef u16 ushort4v __attribute__((ext_vector_type(4)));
typedef u16 ushort8v __attribute__((ext_vector_type(8)));
typedef u32 u32x2 __attribute__((ext_vector_type(2)));

#define DEVI static __device__ __forceinline__

DEVI u16 f2bf(float f) {
    u32 u = __builtin_bit_cast(u32, f);
    u += 0x7fffu + ((u >> 16) & 1u);   // round-to-nearest-even
    return (u16)(u >> 16);
}
DEVI float bf2f(u16 h) { return __builtin_bit_cast(float, (u32)h << 16); }

DEVI float fexp2(float x) { return __builtin_amdgcn_exp2f(x); }  // v_exp_f32

// packed f32->bf16 convert (RTNE), one VALU op for two values
DEVI u32 cvtpk_bf16(float lo, float hi) {
    u32 r;
    asm("v_cvt_pk_bf16_f32 %0, %1, %2" : "=v"(r) : "v"(lo), "v"(hi));
    return r;
}

// async global->LDS, 16B per lane. dst must be wave-uniform base; HW adds lane*16.
DEVI void async_cp16(const u16* g, u16* l) {
    __builtin_amdgcn_global_load_lds((const __attribute__((address_space(1))) u32*)g,
                                     (__attribute__((address_space(3))) u32*)l, 16, 0, 0);
}

template<int N> DEVI void wait_vmcnt() {
    if constexpr (N == 0)      asm volatile("s_waitcnt vmcnt(0)" ::: "memory");
    else if constexpr (N == 2) asm volatile("s_waitcnt vmcnt(2)" ::: "memory");
    else if constexpr (N == 3) asm volatile("s_waitcnt vmcnt(3)" ::: "memory");
    else if constexpr (N == 4) asm volatile("s_waitcnt vmcnt(4)" ::: "memory");
    else if constexpr (N == 6) asm volatile("s_waitcnt vmcnt(6)" ::: "memory");
    else static_assert(N == 0, "add vmcnt case");
}

// m-band XCD swizzle (R2-R6 proven): XCD (L&7) owns a contiguous band of
// gy/8 m-tiles, iterates n within it. Needs gy % 8 == 0.
DEVI void xcd_swizzle(int& bx, int& by, int gx, int gy) {
    int L = by * gx + bx;
    int xcd = L & 7, s = L >> 3;
    int mb = gy >> 3;
    by = xcd * mb + s % mb;
    bx = s / mb;
}

// ---------------------------------------------------------------------------
// GEMM 128-tile: counted-vmcnt 2-deep, 3 LDS buffers (flat smem).
// Coalesced bf16 epilogue via swizzled LDS transpose image; epilogue XOR is
// ((row>>2)&3)<<5 so the 4 q-row-groups of a wave land on distinct 8-bank
// slots (bank shift 8q; old (row&15)<<4 collapsed q mod 32 banks).
// ---------------------------------------------------------------------------
template<int BM, int BN, int RW, int CW, bool QKV3, int NSPLIT, bool XSWZ,
         bool BIAS, bool RELU, bool RESID, bool OBF16, bool VTW>
__global__ __launch_bounds__(256) void gemm_nt(
    const u16* __restrict__ A,
    const u16* __restrict__ W0, const u16* __restrict__ W1, const u16* __restrict__ W2,
    const float* __restrict__ bias, const float* __restrict__ resid,
    void* __restrict__ o0, void* __restrict__ o1, void* __restrict__ o2,
    void* __restrict__ o3, int K, int lda, int Nper, int NX)
{
    static_assert(RW * CW == 4, "4 waves");
    constexpr int WM = BM / RW, WN = BN / CW;
    constexpr int MI = WM / 16, NI = WN / 16;
    constexpr int LPT = BM / 64 + BN / 64;
    constexpr int ASZ = 3 * BM * 32;          // u16 units
    constexpr int BSZ = 3 * BN * 32;
    __shared__ __align__(16) u16 smem[ASZ + BSZ];
    u16* Asm = smem;
    u16* Bsm = smem + ASZ;
    const int tid = threadIdx.x;
    const int w = tid >> 6, lane = tid & 63;
    const int q = lane >> 4, ml = lane & 15;
    const int wr = w / CW, wc = w % CW;
    int bx = blockIdx.x, by = blockIdx.y;
    if (XSWZ) xcd_swizzle(bx, by, gridDim.x, gridDim.y);
    const int m0 = by * BM;
    size_t kbase = 0;
    const u16* W = W0;
    void* outp = o0;
    if (NSPLIT > 1) {
        int part = bx / NX; bx -= part * NX; kbase = (size_t)part * K;
        outp = (part == 0) ? o0 : (part == 1 ? o1 : (part == 2 ? o2 : o3));
    }
    int n0 = bx * BN;
    bool vwrite = false;
    if (QKV3) {
        int sel = n0 / Nper;
        n0 -= sel * Nper;
        W = (sel == 0) ? W0 : (sel == 1 ? W1 : W2);
        outp = (sel == 0) ? o0 : (sel == 1 ? o1 : o2);
        if (VTW) vwrite = (sel == 2);
    }

    auto stage = [&](int buf, int kt) {
#pragma unroll
        for (int p = 0; p < BM / 64; ++p) {
            int g = p * 256 + tid;
            int r = g >> 2, s = g & 3;
            int c = s ^ ((r >> 1) & 3);
            async_cp16(A + (size_t)(m0 + r) * lda + kbase + kt + c * 8,
                       &Asm[buf * (BM * 32) + (p * 256 + w * 64) * 8]);
        }
#pragma unroll
        for (int p = 0; p < BN / 64; ++p) {
            int g = p * 256 + tid;
            int r = g >> 2, s = g & 3;
            int c = s ^ ((r >> 1) & 3);
            async_cp16(W + (size_t)(n0 + r) * lda + kbase + kt + c * 8,
                       &Bsm[buf * (BN * 32) + (p * 256 + w * 64) * 8]);
        }
    };

    const floatx4 fzero = {0.f, 0.f, 0.f, 0.f};
    floatx4 acc[MI][NI];
#pragma unroll
    for (int i = 0; i < MI; ++i)
#pragma unroll
        for (int j = 0; j < NI; ++j) acc[i][j] = fzero;

    const int nt = K >> 5;
    stage(0, 0);
    stage(1, 32);
    int cb = 0, nb = 2;
    for (int it = 0, kt = 0; it < nt; ++it, kt += 32) {
        wait_vmcnt<LPT>();
        __builtin_amdgcn_s_barrier();
        __builtin_amdgcn_sched_barrier(0);
        int ktn = kt + 64; if (ktn > K - 32) ktn = K - 32;   // clamped dup
        stage(nb, ktn);
        __builtin_amdgcn_sched_barrier(0);
        const u16* Asb = &Asm[cb * (BM * 32)];
        const u16* Bsb = &Bsm[cb * (BN * 32)];
        bf16x8 af[MI], bfr[NI];
#pragma unroll
        for (int i = 0; i < MI; ++i) {
            int rm = wr * WM + i * 16 + ml;
            int s = q ^ ((rm >> 1) & 3);
            af[i] = *(const bf16x8*)&Asb[(rm * 4 + s) * 8];
        }
#pragma unroll
        for (int j = 0; j < NI; ++j) {
            int rn = wc * WN + j * 16 + ml;
            int s = q ^ ((rn >> 1) & 3);
            bfr[j] = *(const bf16x8*)&Bsb[(rn * 4 + s) * 8];
        }
#pragma unroll
        for (int i = 0; i < MI; ++i)
#pragma unroll
            for (int j = 0; j < NI; ++j)
                acc[i][j] = __builtin_amdgcn_mfma_f32_16x16x32_bf16(af[i], bfr[j], acc[i][j], 0, 0, 0);
        cb = cb == 2 ? 0 : cb + 1;
        nb = nb == 2 ? 0 : nb + 1;
    }

    wait_vmcnt<0>();   // drain clamped dup stages (also frees LDS for reuse)

    if constexpr (OBF16) {
        __builtin_amdgcn_s_barrier();   // all waves' DMA drained -> LDS free
        char* T = (char*)smem;
        if (VTW && vwrite) {
            // LDS image [BN n][BM m] bf16; packed 8B writes (4 consecutive m)
#pragma unroll
            for (int j = 0; j < NI; ++j) {
                int nl = wc * WN + j * 16 + ml;
#pragma unroll
                for (int i = 0; i < MI; ++i) {
                    int m4 = wr * WM + i * 16 + q * 4;
                    u32x2 pk = {(u32)f2bf(acc[i][j][0]) | ((u32)f2bf(acc[i][j][1]) << 16),
                                (u32)f2bf(acc[i][j][2]) | ((u32)f2bf(acc[i][j][3]) << 16)};
                    *(u32x2*)(T + nl * (BM * 2) + ((m4 * 2) ^ ((nl & 15) << 4))) = pk;
                }
            }
            __syncthreads();
            const int bb = m0 >> 11, sres = m0 & 2047;
            constexpr int CPR = BM / 8, RPP = 256 / CPR;
#pragma unroll
            for (int p = 0; p < BN / RPP; ++p) {
                int nr = p * RPP + (tid / CPR);
                int c0 = (tid % CPR) * 8;
                bf16x8 vv = *(const bf16x8*)(T + nr * (BM * 2) + ((c0 * 2) ^ ((nr & 15) << 4)));
                *(bf16x8*)&((u16*)o3)[(size_t)(bb * 1024 + n0 + nr) * 2048 + sres + c0] = vv;
            }
        } else {
            // LDS image [BM row][BN col] bf16; XOR gives q-groups distinct banks
#pragma unroll
            for (int j = 0; j < NI; ++j) {
                int col = wc * WN + j * 16 + ml;
                float bj = 0.f;
                if (BIAS) bj = bias[n0 + col];
#pragma unroll
                for (int i = 0; i < MI; ++i) {
#pragma unroll
                    for (int r = 0; r < 4; ++r) {
                        int row = wr * WM + i * 16 + q * 4 + r;
                        float v = acc[i][j][r] + bj;
                        if (RELU) v = fmaxf(v, 0.f);
                        *(u16*)(T + row * (BN * 2) + ((col * 2) ^ (((row >> 2) & 3) << 5))) = f2bf(v);
                    }
                }
            }
            __syncthreads();
            constexpr int CPR = BN / 8, RPP = 256 / CPR;
#pragma unroll
            for (int p = 0; p < BM / RPP; ++p) {
                int rr = p * RPP + (tid / CPR);
                int c0 = (tid % CPR) * 8;
                bf16x8 vv = *(const bf16x8*)(T + rr * (BN * 2) + ((c0 * 2) ^ (((rr >> 2) & 3) << 5)));
                *(bf16x8*)&((u16*)outp)[(size_t)(m0 + rr) * Nper + n0 + c0] = vv;
            }
        }
    } else {
        // fp32 out (+resid): 16 lanes x 4B = 64B runs, already line-coalesced
#pragma unroll
        for (int j = 0; j < NI; ++j) {
            int gn = n0 + wc * WN + j * 16 + ml;
            float bj = 0.f;
            if (BIAS) bj = bias[gn];
#pragma unroll
            for (int i = 0; i < MI; ++i) {
                int gm0 = m0 + wr * WM + i * 16 + q * 4;
#pragma unroll
                for (int r = 0; r < 4; ++r) {
                    size_t idx = (size_t)(gm0 + r) * Nper + gn;
                    float v = acc[i][j][r] + bj;
                    if (RELU) v = fmaxf(v, 0.f);
                    if (RESID) v += resid[idx];
                    ((float*)outp)[idx] = v;
                }
            }
        }
    }
}

// ---------------------------------------------------------------------------
// gemm256: 256x256 tile, BK=32, 8 waves, 3-buffer stage(t+2) ring — the
// session-proven gemm_nt pipeline at 256^2 scale. The vmcnt(4) at each iter
// targets loads issued TWO full iterations (~1200 cy) earlier, above HBM
// latency (the R6 gemm8p's waits hit 3-phase-young loads -> ~50% stall).
// Staged LDS: 3 x (16KB A + 16KB B) = 96KB; epilogue transpose image 128KB.
// NSPLIT>1: split-K partials to o0..o3 (bf16).
// ---------------------------------------------------------------------------
template<int NSPLIT, bool BIAS, bool RELU>
__global__ __launch_bounds__(512, 2) void gemm256(
    const u16* __restrict__ A, const u16* __restrict__ W0,
    const float* __restrict__ bias,
    void* __restrict__ o0, void* __restrict__ o1, void* __restrict__ o2,
    void* __restrict__ o3, int K, int lda, int Nper, int NX)
{
    __shared__ __align__(16) u16 smem[65536];   // 128 KB
    u16* Asm = smem;            // 3 x 8192 u16 (16KB per buffer)
    u16* Bsm = smem + 24576;    // 3 x 8192 u16
    const int tid = threadIdx.x;
    const int w = tid >> 6, lane = tid & 63;
    const int q = lane >> 4, ml = lane & 15;
    const int wr = w >> 2, wc = w & 3;          // 2 M-waves x 4 N-waves
    int bx = blockIdx.x, by = blockIdx.y;
    xcd_swizzle(bx, by, gridDim.x, gridDim.y);
    const int m0 = by * 256;
    size_t kbase = 0;
    void* outp = o0;
    if (NSPLIT > 1) {
        int part = bx / NX; bx -= part * NX; kbase = (size_t)part * K;
        outp = (part == 0) ? o0 : (part == 1 ? o1 : (part == 2 ? o2 : o3));
    }
    const int n0 = bx * 256;

    auto stage = [&](int buf, int kt) {
#pragma unroll
        for (int p = 0; p < 2; ++p) {
            int c = p * 512 + tid;
            int r = c >> 2;
            int sc = (c & 3) ^ ((r >> 1) & 3);
            async_cp16(A + (size_t)(m0 + r) * lda + kbase + kt + sc * 8,
                       &Asm[buf * 8192 + (p * 512 + w * 64) * 8]);
        }
#pragma unroll
        for (int p = 0; p < 2; ++p) {
            int c = p * 512 + tid;
            int r = c >> 2;
            int sc = (c & 3) ^ ((r >> 1) & 3);
            async_cp16(W0 + (size_t)(n0 + r) * lda + kbase + kt + sc * 8,
                       &Bsm[buf * 8192 + (p * 512 + w * 64) * 8]);
        }
    };

    const floatx4 fzero = {0.f, 0.f, 0.f, 0.f};
    floatx4 acc[8][4];
#pragma unroll
    for (int i = 0; i < 8; ++i)
#pragma unroll
        for (int j = 0; j < 4; ++j) acc[i][j] = fzero;

    const int nt = K >> 5;
    stage(0, 0);
    stage(1, 32);
    int cb = 0, nb = 2;
    for (int it = 0, kt = 0; it < nt; ++it, kt += 32) {
        wait_vmcnt<4>();                 // drain tile it (issued 2 iters ago)
        __builtin_amdgcn_s_barrier();
        __builtin_amdgcn_sched_barrier(0);
        int ktn = kt + 64; if (ktn > K - 32) ktn = K - 32;   // clamped dup
        stage(nb, ktn);
        __builtin_amdgcn_sched_barrier(0);
        const u16* Asb = &Asm[cb * 8192];
        const u16* Bsb = &Bsm[cb * 8192];
        bf16x8 af[8], bfr[4];
#pragma unroll
        for (int i = 0; i < 8; ++i) {
            int rm = wr * 128 + i * 16 + ml;
            af[i] = *(const bf16x8*)&Asb[(rm * 4 + (q ^ ((rm >> 1) & 3))) * 8];
        }
#pragma unroll
        for (int j = 0; j < 4; ++j) {
            int rn = wc * 64 + j * 16 + ml;
            bfr[j] = *(const bf16x8*)&Bsb[(rn * 4 + (q ^ ((rn >> 1) & 3))) * 8];
        }
        __builtin_amdgcn_s_setprio(1);
#pragma unroll
        for (int i = 0; i < 8; ++i)
#pragma unroll
            for (int j = 0; j < 4; ++j)
                acc[i][j] = __builtin_amdgcn_mfma_f32_16x16x32_bf16(af[i], bfr[j], acc[i][j], 0, 0, 0);
        __builtin_amdgcn_s_setprio(0);
        cb = cb == 2 ? 0 : cb + 1;
        nb = nb == 2 ? 0 : nb + 1;
    }

    wait_vmcnt<0>();                 // drain clamped dup stages
    __builtin_amdgcn_s_barrier();    // LDS now free for the transpose image

    // epilogue via LDS transpose: [256 rows][512 B] image; XOR ((row>>2)&3)<<5
    // puts each wave's 4 q-row-groups on distinct 8-bank slots (conflict-free)
    char* T = (char*)smem;
#pragma unroll
    for (int j = 0; j < 4; ++j) {
        int col = wc * 64 + j * 16 + ml;
        float bj = 0.f;
        if (BIAS) bj = bias[n0 + col];
#pragma unroll
        for (int i = 0; i < 8; ++i) {
#pragma unroll
            for (int r = 0; r < 4; ++r) {
                int row = wr * 128 + i * 16 + q * 4 + r;
                float v = acc[i][j][r] + bj;
                if (RELU) v = fmaxf(v, 0.f);
                *(u16*)(T + row * 512 + ((col * 2) ^ (((row >> 2) & 3) << 5))) = f2bf(v);
            }
        }
    }
    __syncthreads();
#pragma unroll
    for (int p = 0; p < 16; ++p) {
        int rr = p * 16 + (tid >> 5);
        int c0 = (tid & 31) * 8;
        bf16x8 vv = *(const bf16x8*)(T + rr * 512 + ((c0 * 2) ^ (((rr >> 2) & 3) << 5)));
        *(bf16x8*)&((u16*)outp)[(size_t)(m0 + rr) * Nper + n0 + c0] = vv;
    }
}

// ---------------------------------------------------------------------------
// Flash attention v11 (R6): counted-vmcnt 2-deep pipeline, 64 q/wave,
// XCD-grouping swizzle (K/V L2-resident), lsum via ones-row MFMA.
// Q,K: [b*2048+s][h*64+d].  Vt: [b*1024+h*64+d][s].
// ---------------------------------------------------------------------------
__global__ __launch_bounds__(256, 2) void flash9(
    const u16* __restrict__ Q, const u16* __restrict__ Kg,
    const u16* __restrict__ Vt, const float* __restrict__ biasv,
    u16* __restrict__ O)
{
    __shared__ __align__(16) u16 smem[24576];
    const int tid = threadIdx.x;
    const int w = tid >> 6, lane = tid & 63;
    const int qw = w & 1, kv = w >> 1;
    const int q = lane >> 4, ml = lane & 15;
    int bx = blockIdx.x, by = blockIdx.y;
    {   // XCD-grouping: L%8 = XCD; give each XCD 4 contiguous bh values
        int L = by * 16 + bx;            // gridDim.x == 16
        int xcd = L & 7, s = L >> 3;     // s in 0..63
        by = xcd * 4 + (s >> 4);         // bh
        bx = s & 15;                     // q-block
    }
    const int b = by >> 4, h = by & 15;
    const size_t rowQ = (size_t)(b * 2048 + bx * 128);
    const float KSC = 0.125f * 1.4426950408889634f;
    const floatx4 fzero = {0.f, 0.f, 0.f, 0.f};
    const ushort8v onesv = {0x3F80, 0x3F80, 0x3F80, 0x3F80,
                            0x3F80, 0x3F80, 0x3F80, 0x3F80};
    const bf16x8 vone = __builtin_bit_cast(bf16x8, onesv);

    bf16x8 qa[4][2];
#pragma unroll
    for (int qg = 0; qg < 4; ++qg)
#pragma unroll
        for (int c = 0; c < 2; ++c)
            qa[qg][c] = *(const bf16x8*)&Q[(rowQ + qw * 64 + qg * 16 + ml) * 1024
                                           + h * 64 + q * 8 + c * 32];

    auto stage = [&](int buf, int it) {
        {
            int row = tid >> 3, sl = tid & 7;
            int ch = sl ^ ((row & 3) | (((row >> 3) & 1) << 2));
#pragma unroll
            for (int hf = 0; hf < 2; ++hf)
                async_cp16(Kg + (size_t)(b * 2048 + hf * 1024 + it * 32 + row) * 1024
                               + h * 64 + ch * 8,
                           &smem[(hf * 3 + buf) * 2048 + w * 512]);
        }
        {
            int row = tid >> 2, sl = tid & 3;
            int ch = sl ^ ((row >> 1) & 3);
#pragma unroll
            for (int hf = 0; hf < 2; ++hf)
                async_cp16(Vt + (size_t)(b * 1024 + h * 64 + row) * 2048
                               + hf * 1024 + it * 32 + ch * 8,
                           &smem[12288 + (hf * 3 + buf) * 2048 + w * 512]);
        }
    };

    floatx4 oacc[4][4];
    floatx4 lacc[4];
#pragma unroll
    for (int qg = 0; qg < 4; ++qg) {
        lacc[qg] = fzero;
#pragma unroll
        for (int d = 0; d < 4; ++d) oacc[qg][d] = fzero;
    }

    const int swk = (ml & 3) | (((ml >> 2) & 1) << 2);
    const int re = ((ml >> 2) << 3) + (ml & 3);

    stage(0, 0);
    stage(1, 1);
    int cb = 0, nb = 2;
    for (int it = 0; it < 32; ++it) {
        asm volatile("s_waitcnt vmcnt(4)" ::: "memory");
        __builtin_amdgcn_s_barrier();
        __builtin_amdgcn_sched_barrier(0);
        const int s0 = kv * 1024 + it * 32;
        const float4 be = *(const float4*)&biasv[b * 2048 + s0 + q * 8];
        const float4 bo = *(const float4*)&biasv[b * 2048 + s0 + q * 8 + 4];
        __builtin_amdgcn_sched_barrier(0);
        stage(nb, it + 2 < 32 ? it + 2 : 31);

        const u16* Kb = &smem[(kv * 3 + cb) * 2048];
        const u16* Vb = &smem[12288 + (kv * 3 + cb) * 2048];

        bf16x8 ke0 = *(const bf16x8*)&Kb[(re + 0) * 64 + ((0 + q) ^ swk) * 8];
        bf16x8 ke1 = *(const bf16x8*)&Kb[(re + 0) * 64 + ((4 + q) ^ swk) * 8];
        bf16x8 ko0 = *(const bf16x8*)&Kb[(re + 4) * 64 + ((0 + q) ^ swk) * 8];
        bf16x8 ko1 = *(const bf16x8*)&Kb[(re + 4) * 64 + ((4 + q) ^ swk) * 8];
        bf16x8 pfrag[4];
#pragma unroll
        for (int qg = 0; qg < 4; ++qg) {
            floatx4 te = fzero, to = fzero;
            te = __builtin_amdgcn_mfma_f32_16x16x32_bf16(ke0, qa[qg][0], te, 0, 0, 0);
            te = __builtin_amdgcn_mfma_f32_16x16x32_bf16(ke1, qa[qg][1], te, 0, 0, 0);
            to = __builtin_amdgcn_mfma_f32_16x16x32_bf16(ko0, qa[qg][0], to, 0, 0, 0);
            to = __builtin_amdgcn_mfma_f32_16x16x32_bf16(ko1, qa[qg][1], to, 0, 0, 0);
            float pe0 = fexp2(fmaf(te[0], KSC, be.x));
            float pe1 = fexp2(fmaf(te[1], KSC, be.y));
            float pe2 = fexp2(fmaf(te[2], KSC, be.z));
            float pe3 = fexp2(fmaf(te[3], KSC, be.w));
            float po0 = fexp2(fmaf(to[0], KSC, bo.x));
            float po1 = fexp2(fmaf(to[1], KSC, bo.y));
            float po2 = fexp2(fmaf(to[2], KSC, bo.z));
            float po3 = fexp2(fmaf(to[3], KSC, bo.w));
            u32 pk[4];
            pk[0] = cvtpk_bf16(pe0, pe1);
            pk[1] = cvtpk_bf16(pe2, pe3);
            pk[2] = cvtpk_bf16(po0, po1);
            pk[3] = cvtpk_bf16(po2, po3);
            pfrag[qg] = __builtin_bit_cast(bf16x8, *(uint4*)pk);
            lacc[qg] = __builtin_amdgcn_mfma_f32_16x16x32_bf16(
                vone, pfrag[qg], lacc[qg], 0, 0, 0);
        }
#pragma unroll
        for (int dt = 0; dt < 4; ++dt) {
            int vrow = dt * 16 + ml;
            bf16x8 vf = *(const bf16x8*)&Vb[vrow * 32 + ((q ^ ((vrow >> 1) & 3)) * 8)];
#pragma unroll
            for (int qg = 0; qg < 4; ++qg)
                oacc[qg][dt] = __builtin_amdgcn_mfma_f32_16x16x32_bf16(
                    vf, pfrag[qg], oacc[qg][dt], 0, 0, 0);
        }
        cb = cb == 2 ? 0 : cb + 1;
        nb = nb == 2 ? 0 : nb + 1;
    }

    __syncthreads();
    float* sO = (float*)smem;
    float* sL = (float*)smem + 8192;
    if (kv == 1) {
#pragma unroll
        for (int qg = 0; qg < 4; ++qg) {
            sL[(qw * 4 + qg) * 64 + lane] = lacc[qg][0];
#pragma unroll
            for (int dt = 0; dt < 4; ++dt)
                *(floatx4*)&sO[((qw * 4 + qg) * 4 + dt) * 256 + lane * 4] = oacc[qg][dt];
        }
    }
    __syncthreads();
    if (kv == 1) return;
#pragma unroll
    for (int qg = 0; qg < 4; ++qg) {
        float ls = lacc[qg][0] + sL[(qw * 4 + qg) * 64 + lane];
#pragma unroll
        for (int dt = 0; dt < 4; ++dt)
            oacc[qg][dt] += *(const floatx4*)&sO[((qw * 4 + qg) * 4 + dt) * 256 + lane * 4];
        const float rcp = 1.f / ls;
        const size_t row = rowQ + qw * 64 + qg * 16 + ml;
#pragma unroll
        for (int dt = 0; dt < 4; ++dt)
#pragma unroll
            for (int rp = 0; rp < 4; rp += 2) {
                u32 pk = (u32)f2bf(oacc[qg][dt][rp] * rcp)
                       | ((u32)f2bf(oacc[qg][dt][rp + 1] * rcp) << 16);
                *(u32*)&O[row * 1024 + h * 64 + dt * 16 + q * 4 + rp] = pk;
            }
    }
}

// LayerNorm (torch semantics: ddof=1 variance, eps added to std), fp32 -> bf16
DEVI void ln_row(const float* __restrict__ x, float ga, float gb,
                 u16* __restrict__ y, int row, int tid)
{
    const float4 v = ((const float4*)(x + (size_t)row * 1024))[tid];
    float s = v.x + v.y + v.z + v.w;
    float ss = v.x * v.x + v.y * v.y + v.z * v.z + v.w * v.w;
#pragma unroll
    for (int d = 1; d < 64; d <<= 1) { s += __shfl_xor(s, d, 64); ss += __shfl_xor(ss, d, 64); }
    __shared__ float ps[4], pss[4];
    const int w = tid >> 6, lane = tid & 63;
    if (lane == 0) { ps[w] = s; pss[w] = ss; }
    __syncthreads();
    s = ps[0] + ps[1] + ps[2] + ps[3];
    ss = pss[0] + pss[1] + pss[2] + pss[3];
    float mean = s * (1.f / 1024.f);
    float var = fmaxf((ss - s * mean) * (1.f / 1023.f), 0.f);
    float sc = ga / (sqrtf(var) + 1e-6f);
    ushort4v o;
    o[0] = f2bf((v.x - mean) * sc + gb);
    o[1] = f2bf((v.y - mean) * sc + gb);
    o[2] = f2bf((v.z - mean) * sc + gb);
    o[3] = f2bf((v.w - mean) * sc + gb);
    ((ushort4v*)(y + (size_t)row * 1024))[tid] = o;
}

__global__ __launch_bounds__(256) void ln_bf16(const float* __restrict__ x,
    const float* __restrict__ ga, const float* __restrict__ gb, u16* __restrict__ y)
{
    ln_row(x, ga[0], gb[0], y, blockIdx.x, threadIdx.x);
}

// prep: weight casts (blocks 0..12287) + mask bias (12288..12303) + LN1 (12304..16399)
__global__ __launch_bounds__(256) void prep(
    const float* __restrict__ wq, const float* __restrict__ wk,
    const float* __restrict__ wv, const float* __restrict__ wo,
    const float* __restrict__ w1, const float* __restrict__ w2,
    u16* __restrict__ wqb, u16* __restrict__ wkb, u16* __restrict__ wvb,
    u16* __restrict__ wob, u16* __restrict__ w1b, u16* __restrict__ w2b,
    const int* __restrict__ m, float* __restrict__ biasv,
    const float* __restrict__ src, const float* __restrict__ a1,
    const float* __restrict__ be1, u16* __restrict__ xln1)
{
    const int bx = blockIdx.x;
    if (bx < 12288) {
        size_t i = (size_t)bx * 256 + threadIdx.x;   // float4 index
        const float* s; u16* d; size_t off;
        if (i < 262144)       { s = wq; d = wqb; off = i; }
        else if (i < 524288)  { s = wk; d = wkb; off = i - 262144; }
        else if (i < 786432)  { s = wv; d = wvb; off = i - 524288; }
        else if (i < 1048576) { s = wo; d = wob; off = i - 786432; }
        else if (i < 2097152) { s = w1; d = w1b; off = i - 1048576; }
        else                  { s = w2; d = w2b; off = i - 2097152; }
        float4 v = ((const float4*)s)[off];
        ushort4v o = {f2bf(v.x), f2bf(v.y), f2bf(v.z), f2bf(v.w)};
        ((ushort4v*)d)[off] = o;
    } else if (bx < 12304) {
        int i = (bx - 12288) * 256 + threadIdx.x;
        biasv[i] = m[i] ? 0.f : -1.442695e9f;
    } else {
        ln_row(src, a1[0], be1[0], xln1, bx - 12304, threadIdx.x);
    }
}

// FF2 finish: out = (bf16 partials P0+P1+P2+P3) + b2[col] + resid
__global__ __launch_bounds__(256) void ff2_fin(
    const u16* __restrict__ p0, const u16* __restrict__ p1,
    const u16* __restrict__ p2, const u16* __restrict__ p3,
    const float* __restrict__ b2, const float* __restrict__ resid,
    float* __restrict__ out)
{
    const size_t i = (size_t)blockIdx.x * 256 + threadIdx.x;   // float4 index
    ushort4v a = *(const ushort4v*)&p0[i * 4];
    ushort4v b = *(const ushort4v*)&p1[i * 4];
    ushort4v c = *(const ushort4v*)&p2[i * 4];
    ushort4v d = *(const ushort4v*)&p3[i * 4];
    float4 r = ((const float4*)resid)[i];
    float4 bb = ((const float4*)b2)[i & 255];
    float4 o;
    o.x = ((bf2f(a[0]) + bf2f(b[0])) + (bf2f(c[0]) + bf2f(d[0]))) + r.x + bb.x;
    o.y = ((bf2f(a[1]) + bf2f(b[1])) + (bf2f(c[1]) + bf2f(d[1]))) + r.y + bb.y;
    o.z = ((bf2f(a[2]) + bf2f(b[2])) + (bf2f(c[2]) + bf2f(d[2]))) + r.z + bb.z;
    o.w = ((bf2f(a[3]) + bf2f(b[3])) + (bf2f(c[3]) + bf2f(d[3]))) + r.w + bb.w;
    ((float4*)out)[i] = o;
}

extern "C" void kernel_launch(void* const* d_in, const int* in_sizes, int n_in,
                              void* d_out, int out_size, void* d_ws, size_t ws_size,
                              hipStream_t stream)
{
    const float* src = (const float*)d_in[0];
    const int* msk   = (const int*)d_in[1];
    const float* wq  = (const float*)d_in[2];
    const float* wk  = (const float*)d_in[3];
    const float* wv  = (const float*)d_in[4];
    const float* wo  = (const float*)d_in[5];
    const float* w1  = (const float*)d_in[6];
    const float* b1  = (const float*)d_in[7];
    const float* w2  = (const float*)d_in[8];
    const float* b2  = (const float*)d_in[9];
    const float* a1  = (const float*)d_in[10];
    const float* be1 = (const float*)d_in[11];
    const float* a2  = (const float*)d_in[12];
    const float* be2 = (const float*)d_in[13];
    float* out = (float*)d_out;

    char* ws = (char*)d_ws;
    const size_t MB = (size_t)1 << 20;
    u16* wqb  = (u16*)(ws + 0 * MB);
    u16* wkb  = (u16*)(ws + 2 * MB);
    u16* wvb  = (u16*)(ws + 4 * MB);
    u16* wob  = (u16*)(ws + 6 * MB);
    u16* w1b  = (u16*)(ws + 8 * MB);    // 8..16
    u16* w2b  = (u16*)(ws + 16 * MB);   // 16..24 (live through FF2)
    u16* xln1 = (u16*)(ws + 24 * MB);   // 24..32; dead after QKV; aliased by attn
    u16* attn = xln1;
    u16* Qb   = (u16*)(ws + 32 * MB);   // 32..40; dead after flash; aliased by xln2
    u16* xln2 = Qb;
    u16* Kb   = (u16*)(ws + 40 * MB);   // 40..48
    u16* Vt   = (u16*)(ws + 56 * MB);   // 56..64 (written directly by QKV VTW)
    float* biasv = (float*)(ws + 64 * MB);  // 16 KB in 64..72 spare
    u16* h1   = (u16*)(ws + 40 * MB);   // 32 MB: 40..72 (Kb/Vt dead by then)
    float* src2 = (float*)(ws + 72 * MB); // 16 MB: 72..88
    // FF2 bf16 partials (8 MB each) in regions dead by FF2 time:
    u16* P0 = (u16*)(ws + 0 * MB);    // wq..wo casts (dead after O-proj)
    u16* P1 = (u16*)(ws + 8 * MB);    // w1b (dead after FF1)
    u16* P2 = (u16*)(ws + 24 * MB);   // attn (dead after O-proj)
    u16* P3 = (u16*)(ws + 32 * MB);   // xln2 (dead after FF1)

    // fused: weight casts + mask bias + LN1
    prep<<<16400, 256, 0, stream>>>(wq, wk, wv, wo, w1, w2,
                                    wqb, wkb, wvb, wob, w1b, w2b,
                                    msk, biasv, src, a1, be1, xln1);

    // fused QKV (128-tile, 768 blocks, fills chip): V written transposed to Vt
    gemm_nt<128, 128, 2, 2, true, 1, true, false, false, false, true, true><<<dim3(24, 32), 256, 0, stream>>>(
        xln1, wqb, wkb, wvb, nullptr, nullptr, Qb, Kb, nullptr, Vt, 1024, 1024, 1024, 0);

    flash9<<<dim3(16, 32), 256, 0, stream>>>(Qb, Kb, Vt, biasv, attn);

    // O-projection + residual (fp32) — 128x64 tile path
    gemm_nt<128, 64, 4, 1, false, 1, true, false, false, true, false, false><<<dim3(16, 32), 256, 0, stream>>>(
        attn, wob, nullptr, nullptr, nullptr, src, src2, nullptr, nullptr, nullptr,
        1024, 1024, 1024, 0);

    ln_bf16<<<4096, 256, 0, stream>>>(src2, a2, be2, xln2);

    // FF1 (256^2 3-buffer ring, 256 blocks = 1/CU): bias + ReLU -> bf16
    gemm256<1, true, true><<<dim3(16, 16), 512, 0, stream>>>(
        xln2, w1b, b1, h1, nullptr, nullptr, nullptr, 1024, 1024, 4096, 0);

    // FF2 (256^2, split-K=4, 256 blocks = 1/CU) into bf16 partials
    gemm256<4, false, false><<<dim3(16, 16), 512, 0, stream>>>(
        h1, w2b, nullptr, P0, P1, P2, P3, 1024, 4096, 1024, 4);

    // out = P0+P1+P2+P3 + b2 + src2
    ff2_fin<<<4096, 256, 0, stream>>>(P0, P1, P2, P3, b2, src2, out);
}